// Round 16
// baseline (207.677 us; speedup 1.0000x reference)
//
#include <hip/hip_runtime.h>
#include <hip/hip_bf16.h>
#include <math.h>

#define B_ 4
#define T_ 2048
#define C_ 1024
#define M_ (B_*T_)   // 8192 rows

typedef __attribute__((ext_vector_type(8))) __bf16 bf16x8;
typedef __attribute__((ext_vector_type(4))) float floatx4;

// ---------- bf16 helpers ----------
__device__ inline float bf2f(unsigned short u){
    return __uint_as_float(((unsigned)u) << 16);
}
__device__ inline unsigned short f2bf(float f){
    unsigned u = __float_as_uint(f);
    unsigned r = (u + 0x7fffu + ((u >> 16) & 1u)) >> 16;   // RNE
    return (unsigned short)r;
}

// ---------- async global->LDS, 16 B per lane, wave-uniform LDS base ----------
__device__ inline void llds16(const unsigned short* g, unsigned short* lds){
    __builtin_amdgcn_global_load_lds(
        (const __attribute__((address_space(1))) unsigned int*)g,
        (__attribute__((address_space(3))) unsigned int*)(unsigned int)(uintptr_t)lds,
        16, 0, 0);
}

// ---------- counted waitcnt (T4): leave prefetch loads in flight across barriers ----------
template<int N> __device__ inline void vmwait(){
    static_assert(N==0 || N==4 || N==6 || N==8, "add literal");
    if constexpr (N==0) asm volatile("s_waitcnt vmcnt(0)" ::: "memory");
    else if constexpr (N==4) asm volatile("s_waitcnt vmcnt(4)" ::: "memory");
    else if constexpr (N==6) asm volatile("s_waitcnt vmcnt(6)" ::: "memory");
    else if constexpr (N==8) asm volatile("s_waitcnt vmcnt(8)" ::: "memory");
}
__device__ inline void lgkm0(){ asm volatile("s_waitcnt lgkmcnt(0)" ::: "memory"); }

// ---------- fp32 -> bf16 cast (all four tensors) + zero the l row-sum buffer ----------
#define NX_ (M_*C_/4)
#define NW_ (C_*C_/4)
#define NL4_ (M_/4)
__global__ __launch_bounds__(256) void cast_all(
    const float* __restrict__ x, const float* __restrict__ wq,
    const float* __restrict__ wk, const float* __restrict__ wv,
    unsigned short* __restrict__ xb, unsigned short* __restrict__ wb,
    float* __restrict__ l)
{
    int i = blockIdx.x * 256 + threadIdx.x;
    const float* src; unsigned short* dst; int idx;
    if (i < NX_){ src = x; dst = xb; idx = i; }
    else if (i < NX_ + 3 * NW_){
        i -= NX_;
        int w = i / NW_; idx = i - w * NW_;
        src = (w == 0) ? wq : ((w == 1) ? wk : wv);
        dst = wb + (size_t)w * C_ * C_;
    } else {
        ((float4*)l)[i - NX_ - 3 * NW_] = make_float4(0.f, 0.f, 0.f, 0.f);
        return;
    }
    float4 v = ((const float4*)src)[idx];
    ((ushort4*)dst)[idx] = make_ushort4(f2bf(v.x), f2bf(v.y), f2bf(v.z), f2bf(v.w));
}

// ---------- 4-wave COUNTED-VMCNT double-buffered core, BK=32 (proj) ----------
// r22 (H9): r15 showed counted-db@BK64 costs proj its 4-residency (64 KB LDS
// -> 2 blocks/CU -> 63.7 us, Occ 17.8%). BK=32 halves each buffer: 32 KB db
// total -> (256,4) keeps 4 blocks/CU = 16 waves/CU (r9's residency) AND the
// r13-proven counted-vmcnt pipeline (zero full drains). Ratio unchanged
// (16 MFMA : 8 ds_read per tile). BK=32 swizzle: 4 chunks/row; store global
// chunk c of row r at pos c ^ ((r>>1)&3); read cpos = fq ^ ((fr>>1)&3).
// Key = ((row mod 16)>>1)&3 on both sides (row bases all multiples of 16).
// Bank check: rows fr/fr+8 share bank = 2-way = free (m136); 8 lanes per
// 16B-class = hardware minimum, no excess serialization.
template<int WM, int WN>
__device__ inline void gemm_core_cnt32(const unsigned short* __restrict__ A,
                                       const unsigned short* __restrict__ Bm,
                                       int lda, int ldb, int m0, int n0, int kTiles,
                                       unsigned short* As, unsigned short* Bs,
                                       floatx4 (*acc)[WN/16])
{
    const int NL  = WM/32 + WN/32;        // llds16 calls per wave per tile (=4 for <64,64>)
    const int ASZ = 2 * WM * 32;          // elems per A buffer (block m = 2*WM rows x 32)
    const int BSZ = 2 * WN * 32;

    const int tid  = threadIdx.x;
    const int lane = tid & 63;
    const int wave = tid >> 6;
    const int wm = (wave >> 1) * WM;
    const int wn = (wave & 1) * WN;
    const int fr = lane & 15;
    const int fq = lane >> 4;
    const int sr = lane >> 2;             // staging row within 16-row call
    const int sp = lane & 3;              // staging chunk position
    const int sc = (sp ^ ((sr >> 1) & 3)) * 8;   // swizzled source chunk offset

    const unsigned short* gA = A  + (size_t)(m0 + wave * (WM/2) + sr) * lda + sc;
    const unsigned short* gB = Bm + (size_t)(n0 + wave * (WN/2) + sr) * ldb + sc;
    unsigned short* ldsA = As + wave * (WM/2) * 32;
    unsigned short* ldsB = Bs + wave * (WN/2) * 32;

    __syncthreads();                      // entry: prior users of buffers done
    #pragma unroll
    for (int i = 0; i < WM/32; i++)       // prologue: tile 0 -> buf0 (16 rows/call)
        llds16(gA + (size_t)(i * 16) * lda, ldsA + i * 16 * 32);
    #pragma unroll
    for (int i = 0; i < WN/32; i++)
        llds16(gB + (size_t)(i * 16) * ldb, ldsB + i * 16 * 32);

    int cur = 0;
    for (int kt = 0; kt < kTiles; kt++){
        if (kt + 1 < kTiles){
            const int nk0 = (kt + 1) * 32;
            unsigned short* lA = ldsA + (cur ^ 1) * ASZ;
            unsigned short* lB = ldsB + (cur ^ 1) * BSZ;
            #pragma unroll
            for (int i = 0; i < WM/32; i++)
                llds16(gA + (size_t)(i * 16) * lda + nk0, lA + i * 16 * 32);
            #pragma unroll
            for (int i = 0; i < WN/32; i++)
                llds16(gB + (size_t)(i * 16) * ldb + nk0, lB + i * 16 * 32);
            vmwait<NL>();                 // own tile-kt loads retired; kt+1 in flight
        } else {
            vmwait<0>();
        }
        __builtin_amdgcn_s_barrier();     // all waves: tile kt visible
        const unsigned short* rA = As + cur * ASZ;
        const unsigned short* rB = Bs + cur * BSZ;
        const int cpos = (fq ^ ((fr >> 1) & 3)) * 8;
        bf16x8 af[WM/16], bv[WN/16];
        #pragma unroll
        for (int i = 0; i < WM/16; i++)
            af[i] = *(const bf16x8*)(rA + (wm + i*16 + fr) * 32 + cpos);
        #pragma unroll
        for (int j = 0; j < WN/16; j++)
            bv[j] = *(const bf16x8*)(rB + (wn + j*16 + fr) * 32 + cpos);
        #pragma unroll
        for (int i = 0; i < WM/16; i++)
            #pragma unroll
            for (int j = 0; j < WN/16; j++)
                acc[i][j] = __builtin_amdgcn_mfma_f32_16x16x32_bf16(af[i], bv[j], acc[i][j], 0, 0, 0);
        lgkm0();                          // my LDS reads done (regs safe)
        __builtin_amdgcn_s_barrier();     // buf[cur] free for overwrite
        cur ^= 1;
    }
}

// ---------- 4-wave COUNTED-VMCNT double-buffered core, BK=64 (pv) ----------
// r13-proven (best 196.5). XOR-swizzled chunks, 0 bank conflicts.
template<int WM, int WN>
__device__ inline void gemm_core_cnt(const unsigned short* __restrict__ A,
                                     const unsigned short* __restrict__ Bm,
                                     int lda, int ldb, int m0, int n0, int kTiles,
                                     unsigned short* As, unsigned short* Bs,
                                     floatx4 (*acc)[WN/16])
{
    const int NL  = WM/16 + WN/16;        // per-wave loads per tile
    const int ASZ = 2 * WM * 64;          // one A buffer (block m = 2*WM rows)
    const int BSZ = 2 * WN * 64;

    const int tid  = threadIdx.x;
    const int lane = tid & 63;
    const int wave = tid >> 6;
    const int wm = (wave >> 1) * WM;
    const int wn = (wave & 1) * WN;
    const int fr = lane & 15;
    const int fq = lane >> 4;
    const int cxor = fr & 7;
    const int sr = lane >> 3;
    const int sc = ((lane & 7) ^ ((lane >> 3) & 7)) * 8;

    const unsigned short* gA = A  + (size_t)(m0 + wave * (WM/2) + sr) * lda + sc;
    const unsigned short* gB = Bm + (size_t)(n0 + wave * (WN/2) + sr) * ldb + sc;
    unsigned short* ldsA = As + wave * (WM/2) * 64;
    unsigned short* ldsB = Bs + wave * (WN/2) * 64;

    __syncthreads();                      // entry: prior users of buffers done
    #pragma unroll
    for (int i = 0; i < WM/16; i++)       // prologue: tile 0 -> buf0
        llds16(gA + (size_t)(i * 8) * lda, ldsA + i * 8 * 64);
    #pragma unroll
    for (int i = 0; i < WN/16; i++)
        llds16(gB + (size_t)(i * 8) * ldb, ldsB + i * 8 * 64);

    int cur = 0;
    for (int kt = 0; kt < kTiles; kt++){
        if (kt + 1 < kTiles){             // issue next tile -> buf^1
            const int nk0 = (kt + 1) * 64;
            unsigned short* lA = ldsA + (cur ^ 1) * ASZ;
            unsigned short* lB = ldsB + (cur ^ 1) * BSZ;
            #pragma unroll
            for (int i = 0; i < WM/16; i++)
                llds16(gA + (size_t)(i * 8) * lda + nk0, lA + i * 8 * 64);
            #pragma unroll
            for (int i = 0; i < WN/16; i++)
                llds16(gB + (size_t)(i * 8) * ldb + nk0, lB + i * 8 * 64);
            vmwait<NL>();                 // own tile-kt loads retired; kt+1 in flight
        } else {
            vmwait<0>();
        }
        __builtin_amdgcn_s_barrier();     // all waves: tile kt visible
        const unsigned short* rA = As + cur * ASZ;
        const unsigned short* rB = Bs + cur * BSZ;
        #pragma unroll
        for (int ks = 0; ks < 64; ks += 32){
            const int cpos = (((ks >> 3) + fq) ^ cxor) * 8;
            bf16x8 af[WM/16], bv[WN/16];
            #pragma unroll
            for (int i = 0; i < WM/16; i++)
                af[i] = *(const bf16x8*)(rA + (wm + i*16 + fr) * 64 + cpos);
            #pragma unroll
            for (int j = 0; j < WN/16; j++)
                bv[j] = *(const bf16x8*)(rB + (wn + j*16 + fr) * 64 + cpos);
            #pragma unroll
            for (int i = 0; i < WM/16; i++)
                #pragma unroll
                for (int j = 0; j < WN/16; j++)
                    acc[i][j] = __builtin_amdgcn_mfma_f32_16x16x32_bf16(af[i], bv[j], acc[i][j], 0, 0, 0);
        }
        lgkm0();                          // my LDS reads done (regs safe)
        __builtin_amdgcn_s_barrier();     // buf[cur] free for overwrite
        cur ^= 1;
    }
}

// ---------- 8-wave COUNTED-VMCNT double-buffered core, BK=64 (score) ----------
// Block tile (4*WM) x (2*WN); A rows wave*(WM/2), B rows wave*(WN/4).
// REGISTER RULE (r10): (512,4) budget 128 VGPR vs ~80 need for <32,64>.
template<int WM, int WN>
__device__ inline void gemm_core8_cnt(const unsigned short* __restrict__ A,
                                      const unsigned short* __restrict__ Bm,
                                      int lda, int ldb, int m0, int n0, int kTiles,
                                      unsigned short* As, unsigned short* Bs,
                                      floatx4 (*acc)[WN/16])
{
    const int NL  = WM/16 + WN/32;        // per-wave loads per tile
    const int ASZ = 4 * WM * 64;          // one A buffer (block m = 4*WM rows)
    const int BSZ = 2 * WN * 64;

    const int tid  = threadIdx.x;
    const int lane = tid & 63;
    const int wave = tid >> 6;            // 0..7
    const int wm = (wave >> 1) * WM;
    const int wn = (wave & 1) * WN;
    const int fr = lane & 15;
    const int fq = lane >> 4;
    const int cxor = fr & 7;
    const int sr = lane >> 3;
    const int sc = ((lane & 7) ^ ((lane >> 3) & 7)) * 8;

    const unsigned short* gA = A  + (size_t)(m0 + wave * (WM/2) + sr) * lda + sc;
    const unsigned short* gB = Bm + (size_t)(n0 + wave * (WN/4) + sr) * ldb + sc;
    unsigned short* ldsA = As + wave * (WM/2) * 64;
    unsigned short* ldsB = Bs + wave * (WN/4) * 64;

    __syncthreads();
    #pragma unroll
    for (int i = 0; i < WM/16; i++)       // prologue: tile 0 -> buf0
        llds16(gA + (size_t)(i * 8) * lda, ldsA + i * 8 * 64);
    #pragma unroll
    for (int i = 0; i < WN/32; i++)
        llds16(gB + (size_t)(i * 8) * ldb, ldsB + i * 8 * 64);

    int cur = 0;
    for (int kt = 0; kt < kTiles; kt++){
        if (kt + 1 < kTiles){
            const int nk0 = (kt + 1) * 64;
            unsigned short* lA = ldsA + (cur ^ 1) * ASZ;
            unsigned short* lB = ldsB + (cur ^ 1) * BSZ;
            #pragma unroll
            for (int i = 0; i < WM/16; i++)
                llds16(gA + (size_t)(i * 8) * lda + nk0, lA + i * 8 * 64);
            #pragma unroll
            for (int i = 0; i < WN/32; i++)
                llds16(gB + (size_t)(i * 8) * ldb + nk0, lB + i * 8 * 64);
            vmwait<NL>();
        } else {
            vmwait<0>();
        }
        __builtin_amdgcn_s_barrier();
        const unsigned short* rA = As + cur * ASZ;
        const unsigned short* rB = Bs + cur * BSZ;
        #pragma unroll
        for (int ks = 0; ks < 64; ks += 32){
            const int cpos = (((ks >> 3) + fq) ^ cxor) * 8;
            bf16x8 af[WM/16], bv[WN/16];
            #pragma unroll
            for (int i = 0; i < WM/16; i++)
                af[i] = *(const bf16x8*)(rA + (wm + i*16 + fr) * 64 + cpos);
            #pragma unroll
            for (int j = 0; j < WN/16; j++)
                bv[j] = *(const bf16x8*)(rB + (wn + j*16 + fr) * 64 + cpos);
            #pragma unroll
            for (int i = 0; i < WM/16; i++)
                #pragma unroll
                for (int j = 0; j < WN/16; j++)
                    acc[i][j] = __builtin_amdgcn_mfma_f32_16x16x32_bf16(af[i], bv[j], acc[i][j], 0, 0, 0);
        }
        lgkm0();
        __builtin_amdgcn_s_barrier();
        cur ^= 1;
    }
}

// ---------- QKV projection: y = x @ W^T, bf16 out. z=0 Q, z=1 K (row-major), z=2 V^T ----------
// r22: BK=32 counted-vmcnt db core -> 32 KB LDS, (256,4) = 4 blocks/CU (r9's
// residency) + r13's pipeline. Grid 1536, XCD = id%8, per-XCD set 8.4 MB.
// Tripwires: proj >= 53.4 us or bank-conflict spike -> revert to r9 drain core.
__global__ __launch_bounds__(256, 4) void proj_gemm(
    const unsigned short* __restrict__ xb,
    const unsigned short* __restrict__ Wb,   // [3][C_][C_]
    unsigned short* __restrict__ Qb, unsigned short* __restrict__ Kb,
    unsigned short* __restrict__ Vt)
{
    __shared__ unsigned short As[2 * 128 * 32];   // 16 KB (db, BK=32)
    __shared__ unsigned short Bs[2 * 128 * 32];   // 16 KB (db, BK=32)
    const int L = blockIdx.x;
    const int k = L & 7, j = L >> 3;          // j in [0,192)
    const int m0 = (k * 8 + (j & 7)) * 128;
    const int n0 = ((j >> 3) & 7) * 128;
    const int z  = j >> 6;
    const unsigned short* W = Wb + (size_t)z * C_ * C_;

    floatx4 acc[4][4];
    #pragma unroll
    for (int i = 0; i < 4; i++)
        #pragma unroll
        for (int jj = 0; jj < 4; jj++) acc[i][jj] = (floatx4){0.f,0.f,0.f,0.f};
    gemm_core_cnt32<64, 64>(xb, W, C_, C_, m0, n0, C_ / 32, As, Bs, acc);

    const int lane = threadIdx.x & 63, wave = threadIdx.x >> 6;
    const int wm = (wave >> 1) * 64, wn = (wave & 1) * 64;
    const int fr = lane & 15, fq = lane >> 4;

    if (z < 2){
        unsigned short* Y = z ? Kb : Qb;
        #pragma unroll
        for (int i = 0; i < 4; i++)
            #pragma unroll
            for (int jj = 0; jj < 4; jj++)
                #pragma unroll
                for (int r = 0; r < 4; r++){
                    int row = m0 + wm + i*16 + fq*4 + r;
                    int col = n0 + wn + jj*16 + fr;
                    Y[(size_t)row * C_ + col] = f2bf(acc[i][jj][r]);
                }
    } else {
        // V^T[b][d][t]; 4 acc regs = 4 consecutive t -> packed ushort4 store
        #pragma unroll
        for (int i = 0; i < 4; i++)
            #pragma unroll
            for (int jj = 0; jj < 4; jj++){
                int row = m0 + wm + i*16 + fq*4;         // token index
                int col = n0 + wn + jj*16 + fr;          // d
                int b = row / T_, t = row % T_;
                ushort4 o = make_ushort4(f2bf(acc[i][jj][0]), f2bf(acc[i][jj][1]),
                                         f2bf(acc[i][jj][2]), f2bf(acc[i][jj][3]));
                *(ushort4*)&Vt[(size_t)b * C_ * T_ + (size_t)col * T_ + t] = o;
            }
    }
}

// ---------- S = Q K^T, causal mask + unnormalized exp -> P (bf16) + fused row-sum ----------
// r13-proven: 8-wave <32,64> counted-vmcnt core (NL=4), LDS 64 KB db ->
// 2 blocks/CU = 16 waves/CU. Grid 544. H6 mapping: b = xcd>>1, pair family
// kk = 2p + (xcd&1) -> per-XCD K set = 4 MB = one L2.
// Logits bounded -> no max pass. Row sums via per-row atomicAdd (<=17/row).
__global__ __launch_bounds__(512, 4) void score_gemm(
    const unsigned short* __restrict__ Qb, const unsigned short* __restrict__ Kb,
    unsigned short* __restrict__ P, float* __restrict__ l)
{
    const int L = blockIdx.x;
    const int xcd = L & 7, j = L >> 3;        // j in [0,68)
    const int b  = xcd >> 1;
    const int p  = j / 17, rr = j % 17;       // p in [0,4)
    const int kk = 2 * p + (xcd & 1);         // pair id 0..7
    int ti, si;
    if (rr <= 15 - kk){ ti = 15 - kk; si = rr; }
    else              { ti = kk;      si = rr - (16 - kk); }
    const int t0 = ti * 128, s0 = si * 128;

    __shared__ unsigned short As[2 * 128 * 64];   // 32 KB (db)
    __shared__ unsigned short Bs[2 * 128 * 64];   // 32 KB (db)
    floatx4 acc[2][4];
    #pragma unroll
    for (int i = 0; i < 2; i++)
        #pragma unroll
        for (int jj = 0; jj < 4; jj++) acc[i][jj] = (floatx4){0.f,0.f,0.f,0.f};
    gemm_core8_cnt<32, 64>(Qb + (size_t)b * T_ * C_, Kb + (size_t)b * T_ * C_,
                           C_, C_, t0, s0, C_ / 64, As, Bs, acc);

    const int lane = threadIdx.x & 63, wave = threadIdx.x >> 6;
    const int wm = (wave >> 1) * 32, wn = (wave & 1) * 64;
    const int fr = lane & 15, fq = lane >> 4;
    unsigned short* Pb = P + (size_t)b * T_ * T_;
    const float scale = 0.03125f;        // 1/sqrt(1024)
    float rsl[2][4];
    #pragma unroll
    for (int i = 0; i < 2; i++)
        #pragma unroll
        for (int r2 = 0; r2 < 4; r2++) rsl[i][r2] = 0.f;

    #pragma unroll
    for (int i = 0; i < 2; i++)
        #pragma unroll
        for (int jj = 0; jj < 4; jj++)
            #pragma unroll
            for (int r2 = 0; r2 < 4; r2++){
                int t = t0 + wm + i*16 + fq*4 + r2;
                int s = s0 + wn + jj*16 + fr;
                float v = (s <= t) ? __expf(acc[i][jj][r2] * scale) : 0.f;
                rsl[i][r2] += v;
                Pb[(size_t)t * T_ + s] = f2bf(v);
            }
    // reduce across the 16-lane fr group; one atomic per (row, wave)
    #pragma unroll
    for (int i = 0; i < 2; i++)
        #pragma unroll
        for (int r2 = 0; r2 < 4; r2++){
            float v = rsl[i][r2];
            v += __shfl_xor(v, 1, 64);
            v += __shfl_xor(v, 2, 64);
            v += __shfl_xor(v, 4, 64);
            v += __shfl_xor(v, 8, 64);
            if (fr == 0){
                int t = t0 + wm + i*16 + fq*4 + r2;
                atomicAdd(&l[(size_t)b * T_ + t], v);
            }
        }
}

// ---------- O = (P V) / l ----------
// r13-proven: counted-vmcnt db core (NL=6), LDS 48 KB, uniform grid 512
// (every block exactly 34 kt). H6 mapping: b = xcd>>1, kk = 2p+(xcd&1);
// per-XCD Vt set = 4 MB = one L2; P[b] read by the XCD-pair that wrote it.
__global__ __launch_bounds__(256, 4) void pv_gemm(
    const unsigned short* __restrict__ P, const unsigned short* __restrict__ Vt,
    const float* __restrict__ l, float* __restrict__ out)
{
    const int L = blockIdx.x;
    const int xcd = L & 7, j = L >> 3;        // j in [0,64)
    const int b  = xcd >> 1;
    const int p  = j >> 4;                    // 0..3
    const int n0 = (j & 15) * 64;             // d tile (64 wide)
    const int kk = 2 * p + (xcd & 1);         // pair id 0..7

    __shared__ unsigned short As[2 * 128 * 64];   // 32 KB (db)
    __shared__ unsigned short Bs[2 * 64 * 64];    // 16 KB (db)

    const int lane = threadIdx.x & 63, wave = threadIdx.x >> 6;
    const int wm = (wave >> 1) * 64, wn = (wave & 1) * 32;
    const int fr = lane & 15, fq = lane >> 4;
    float* ob = out + (size_t)b * T_ * C_;
    const float* lb = l + (size_t)b * T_;

    #pragma unroll
    for (int phase = 0; phase < 2; phase++){
        const int ti = phase ? kk : (15 - kk);  // long tile first
        const int t0 = ti * 128;
        const int kTiles = 2 * (ti + 1);        // causal: keys s < t0+128

        floatx4 acc[4][2];
        #pragma unroll
        for (int i = 0; i < 4; i++)
            #pragma unroll
            for (int jj = 0; jj < 2; jj++) acc[i][jj] = (floatx4){0.f,0.f,0.f,0.f};
        gemm_core_cnt<64, 32>(P + (size_t)b * T_ * T_, Vt + (size_t)b * C_ * T_,
                              T_, T_, t0, n0, kTiles, As, Bs, acc);

        #pragma unroll
        for (int i = 0; i < 4; i++){
            float inv[4];
            #pragma unroll
            for (int r2 = 0; r2 < 4; r2++)
                inv[r2] = 1.f / lb[t0 + wm + i*16 + fq*4 + r2];
            #pragma unroll
            for (int jj = 0; jj < 2; jj++)
                #pragma unroll
                for (int r2 = 0; r2 < 4; r2++){
                    int t = t0 + wm + i*16 + fq*4 + r2;
                    int d = n0 + wn + jj*16 + fr;
                    ob[(size_t)t * C_ + d] = acc[i][jj][r2] * inv[r2];
                }
        }
    }
}

extern "C" void kernel_launch(void* const* d_in, const int* in_sizes, int n_in,
                              void* d_out, int out_size, void* d_ws, size_t ws_size,
                              hipStream_t stream)
{
    const float* x  = (const float*)d_in[0];
    const float* Wq = (const float*)d_in[1];
    const float* Wk = (const float*)d_in[2];
    const float* Wv = (const float*)d_in[3];
    float* out = (float*)d_out;

    // ws layout (bf16 elems): Qb | Kb | Vt | P | l(fp32). xb/Wb alias P's region
    // (written by cast, read by proj, then overwritten by score_gemm -- stream-ordered;
    // l lies beyond P's 33.5 MB so it never aliases xb/Wb).
    unsigned short* Qb = (unsigned short*)d_ws;
    unsigned short* Kb = Qb + (size_t)M_ * C_;
    unsigned short* Vt = Kb + (size_t)M_ * C_;
    unsigned short* P  = Vt + (size_t)M_ * C_;
    float* l = (float*)(P + (size_t)M_ * T_);
    unsigned short* xb = P;
    unsigned short* Wb = P + (size_t)M_ * C_;

    cast_all<<<(NX_ + 3 * NW_ + NL4_ + 255) / 256, 256, 0, stream>>>(
        x, Wq, Wk, Wv, xb, Wb, l);
    proj_gemm <<<1536, 256, 0, stream>>>(xb, Wb, Qb, Kb, Vt);
    score_gemm<<<544, 512, 0, stream>>>(Qb, Kb, P, l);
    pv_gemm   <<<512, 256, 0, stream>>>(P, Vt, l, out);
}

// Round 18
// 193.841 us; speedup vs baseline: 1.0714x; 1.0714x over previous
//
#include <hip/hip_runtime.h>
#include <hip/hip_bf16.h>
#include <math.h>

#define B_ 4
#define T_ 2048
#define C_ 1024
#define M_ (B_*T_)   // 8192 rows

typedef __attribute__((ext_vector_type(8))) __bf16 bf16x8;
typedef __attribute__((ext_vector_type(4))) float floatx4;

// ---------- bf16 helpers ----------
__device__ inline float bf2f(unsigned short u){
    return __uint_as_float(((unsigned)u) << 16);
}
__device__ inline unsigned short f2bf(float f){
    unsigned u = __float_as_uint(f);
    unsigned r = (u + 0x7fffu + ((u >> 16) & 1u)) >> 16;   // RNE
    return (unsigned short)r;
}

// ---------- async global->LDS, 16 B per lane, wave-uniform LDS base ----------
__device__ inline void llds16(const unsigned short* g, unsigned short* lds){
    __builtin_amdgcn_global_load_lds(
        (const __attribute__((address_space(1))) unsigned int*)g,
        (__attribute__((address_space(3))) unsigned int*)(unsigned int)(uintptr_t)lds,
        16, 0, 0);
}

// ---------- counted waitcnt (T4): leave prefetch loads in flight across barriers ----------
template<int N> __device__ inline void vmwait(){
    static_assert(N==0 || N==4 || N==6 || N==8, "add literal");
    if constexpr (N==0) asm volatile("s_waitcnt vmcnt(0)" ::: "memory");
    else if constexpr (N==4) asm volatile("s_waitcnt vmcnt(4)" ::: "memory");
    else if constexpr (N==6) asm volatile("s_waitcnt vmcnt(6)" ::: "memory");
    else if constexpr (N==8) asm volatile("s_waitcnt vmcnt(8)" ::: "memory");
}
__device__ inline void lgkm0(){ asm volatile("s_waitcnt lgkmcnt(0)" ::: "memory"); }

// ---------- fp32 -> bf16 cast (all four tensors) + zero the l row-sum buffer ----------
#define NX_ (M_*C_/4)
#define NW_ (C_*C_/4)
#define NL4_ (M_/4)
__global__ __launch_bounds__(256) void cast_all(
    const float* __restrict__ x, const float* __restrict__ wq,
    const float* __restrict__ wk, const float* __restrict__ wv,
    unsigned short* __restrict__ xb, unsigned short* __restrict__ wb,
    float* __restrict__ l)
{
    int i = blockIdx.x * 256 + threadIdx.x;
    const float* src; unsigned short* dst; int idx;
    if (i < NX_){ src = x; dst = xb; idx = i; }
    else if (i < NX_ + 3 * NW_){
        i -= NX_;
        int w = i / NW_; idx = i - w * NW_;
        src = (w == 0) ? wq : ((w == 1) ? wk : wv);
        dst = wb + (size_t)w * C_ * C_;
    } else {
        ((float4*)l)[i - NX_ - 3 * NW_] = make_float4(0.f, 0.f, 0.f, 0.f);
        return;
    }
    float4 v = ((const float4*)src)[idx];
    ((ushort4*)dst)[idx] = make_ushort4(f2bf(v.x), f2bf(v.y), f2bf(v.z), f2bf(v.w));
}

// ---------- 4-wave MFMA core (2x2 waves), single-buffered BK=64 (proj) ----------
// r9-proven, and PROVEN-OPTIMAL for proj among all tested variants:
// drain/4-res = 53.4us | 8-wave (512,6) = spill | counted-db@2-res = 63.7 |
// BK32-db@4-res = 70.7. proj's 6-blocks/CU grid with 4 resident gives
// cross-block overlap that hides staging for free; within-block pipelining
// can only pay for it with residency (r15) or barrier-frequency (r16).
// XOR-swizzled chunks, 0 bank conflicts (r6-r16).
template<int WM, int WN>
__device__ inline void gemm_core(const unsigned short* __restrict__ A,
                                 const unsigned short* __restrict__ Bm,
                                 int lda, int ldb, int m0, int n0, int kTiles,
                                 unsigned short* As, unsigned short* Bs,
                                 floatx4 (*acc)[WN/16])
{
    const int tid  = threadIdx.x;
    const int lane = tid & 63;
    const int wave = tid >> 6;            // 0..3
    const int wm = (wave >> 1) * WM;
    const int wn = (wave & 1) * WN;
    const int fr = lane & 15;
    const int fq = lane >> 4;
    const int cxor = fr & 7;
    const int sr = lane >> 3;
    const int sc = ((lane & 7) ^ ((lane >> 3) & 7)) * 8;   // swizzled source chunk

    const unsigned short* gA = A  + (size_t)(m0 + wave * (WM/2) + sr) * lda + sc;
    const unsigned short* gB = Bm + (size_t)(n0 + wave * (WN/2) + sr) * ldb + sc;
    unsigned short* ldsA = As + wave * (WM/2) * 64;
    unsigned short* ldsB = Bs + wave * (WN/2) * 64;

    for (int kt = 0; kt < kTiles; kt++){
        const int k0 = kt * 64;
        __syncthreads();                  // prior iter's LDS reads complete
        #pragma unroll
        for (int i = 0; i < WM/16; i++)
            llds16(gA + (size_t)(i * 8) * lda + k0, ldsA + i * 8 * 64);
        #pragma unroll
        for (int i = 0; i < WN/16; i++)
            llds16(gB + (size_t)(i * 8) * ldb + k0, ldsB + i * 8 * 64);
        __syncthreads();                  // drains vmcnt -> staged data visible
        #pragma unroll
        for (int ks = 0; ks < 64; ks += 32){
            const int cpos = (((ks >> 3) + fq) ^ cxor) * 8;
            bf16x8 af[WM/16], bv[WN/16];
            #pragma unroll
            for (int i = 0; i < WM/16; i++)
                af[i] = *(const bf16x8*)(As + (wm + i*16 + fr) * 64 + cpos);
            #pragma unroll
            for (int j = 0; j < WN/16; j++)
                bv[j] = *(const bf16x8*)(Bs + (wn + j*16 + fr) * 64 + cpos);
            #pragma unroll
            for (int i = 0; i < WM/16; i++)
                #pragma unroll
                for (int j = 0; j < WN/16; j++)
                    acc[i][j] = __builtin_amdgcn_mfma_f32_16x16x32_bf16(af[i], bv[j], acc[i][j], 0, 0, 0);
        }
    }
}

// ---------- 4-wave COUNTED-VMCNT double-buffered core, BK=64 (pv) ----------
// r13-proven (best 196.5): issue next-tile loads into buf^1, wait vmcnt(NL)
// (own current-tile loads retired, next tile's NL stay in flight), raw
// s_barrier (landed data visible block-wide). End of iter: lgkmcnt(0) +
// s_barrier before that buffer is overwritten. Zero full drains (m218).
// vmcnt is per-wave FIFO (m135). XOR-swizzled chunks, 0 bank conflicts.
template<int WM, int WN>
__device__ inline void gemm_core_cnt(const unsigned short* __restrict__ A,
                                     const unsigned short* __restrict__ Bm,
                                     int lda, int ldb, int m0, int n0, int kTiles,
                                     unsigned short* As, unsigned short* Bs,
                                     floatx4 (*acc)[WN/16])
{
    const int NL  = WM/16 + WN/16;        // per-wave loads per tile
    const int ASZ = 2 * WM * 64;          // one A buffer (block m = 2*WM rows)
    const int BSZ = 2 * WN * 64;

    const int tid  = threadIdx.x;
    const int lane = tid & 63;
    const int wave = tid >> 6;
    const int wm = (wave >> 1) * WM;
    const int wn = (wave & 1) * WN;
    const int fr = lane & 15;
    const int fq = lane >> 4;
    const int cxor = fr & 7;
    const int sr = lane >> 3;
    const int sc = ((lane & 7) ^ ((lane >> 3) & 7)) * 8;

    const unsigned short* gA = A  + (size_t)(m0 + wave * (WM/2) + sr) * lda + sc;
    const unsigned short* gB = Bm + (size_t)(n0 + wave * (WN/2) + sr) * ldb + sc;
    unsigned short* ldsA = As + wave * (WM/2) * 64;
    unsigned short* ldsB = Bs + wave * (WN/2) * 64;

    __syncthreads();                      // entry: prior users of buffers done
    #pragma unroll
    for (int i = 0; i < WM/16; i++)       // prologue: tile 0 -> buf0
        llds16(gA + (size_t)(i * 8) * lda, ldsA + i * 8 * 64);
    #pragma unroll
    for (int i = 0; i < WN/16; i++)
        llds16(gB + (size_t)(i * 8) * ldb, ldsB + i * 8 * 64);

    int cur = 0;
    for (int kt = 0; kt < kTiles; kt++){
        if (kt + 1 < kTiles){             // issue next tile -> buf^1
            const int nk0 = (kt + 1) * 64;
            unsigned short* lA = ldsA + (cur ^ 1) * ASZ;
            unsigned short* lB = ldsB + (cur ^ 1) * BSZ;
            #pragma unroll
            for (int i = 0; i < WM/16; i++)
                llds16(gA + (size_t)(i * 8) * lda + nk0, lA + i * 8 * 64);
            #pragma unroll
            for (int i = 0; i < WN/16; i++)
                llds16(gB + (size_t)(i * 8) * ldb + nk0, lB + i * 8 * 64);
            vmwait<NL>();                 // own tile-kt loads retired; kt+1 in flight
        } else {
            vmwait<0>();
        }
        __builtin_amdgcn_s_barrier();     // all waves: tile kt visible
        const unsigned short* rA = As + cur * ASZ;
        const unsigned short* rB = Bs + cur * BSZ;
        #pragma unroll
        for (int ks = 0; ks < 64; ks += 32){
            const int cpos = (((ks >> 3) + fq) ^ cxor) * 8;
            bf16x8 af[WM/16], bv[WN/16];
            #pragma unroll
            for (int i = 0; i < WM/16; i++)
                af[i] = *(const bf16x8*)(rA + (wm + i*16 + fr) * 64 + cpos);
            #pragma unroll
            for (int j = 0; j < WN/16; j++)
                bv[j] = *(const bf16x8*)(rB + (wn + j*16 + fr) * 64 + cpos);
            #pragma unroll
            for (int i = 0; i < WM/16; i++)
                #pragma unroll
                for (int j = 0; j < WN/16; j++)
                    acc[i][j] = __builtin_amdgcn_mfma_f32_16x16x32_bf16(af[i], bv[j], acc[i][j], 0, 0, 0);
        }
        lgkm0();                          // my LDS reads done (regs safe)
        __builtin_amdgcn_s_barrier();     // buf[cur] free for overwrite
        cur ^= 1;
    }
}

// ---------- 8-wave COUNTED-VMCNT double-buffered core, BK=64 (score) ----------
// Block tile (4*WM) x (2*WN); A rows wave*(WM/2), B rows wave*(WN/4).
// REGISTER RULE (r10): (512,4) budget 128 VGPR vs ~80 need for <32,64>.
template<int WM, int WN>
__device__ inline void gemm_core8_cnt(const unsigned short* __restrict__ A,
                                      const unsigned short* __restrict__ Bm,
                                      int lda, int ldb, int m0, int n0, int kTiles,
                                      unsigned short* As, unsigned short* Bs,
                                      floatx4 (*acc)[WN/16])
{
    const int NL  = WM/16 + WN/32;        // per-wave loads per tile
    const int ASZ = 4 * WM * 64;          // one A buffer (block m = 4*WM rows)
    const int BSZ = 2 * WN * 64;

    const int tid  = threadIdx.x;
    const int lane = tid & 63;
    const int wave = tid >> 6;            // 0..7
    const int wm = (wave >> 1) * WM;
    const int wn = (wave & 1) * WN;
    const int fr = lane & 15;
    const int fq = lane >> 4;
    const int cxor = fr & 7;
    const int sr = lane >> 3;
    const int sc = ((lane & 7) ^ ((lane >> 3) & 7)) * 8;

    const unsigned short* gA = A  + (size_t)(m0 + wave * (WM/2) + sr) * lda + sc;
    const unsigned short* gB = Bm + (size_t)(n0 + wave * (WN/4) + sr) * ldb + sc;
    unsigned short* ldsA = As + wave * (WM/2) * 64;
    unsigned short* ldsB = Bs + wave * (WN/4) * 64;

    __syncthreads();
    #pragma unroll
    for (int i = 0; i < WM/16; i++)       // prologue: tile 0 -> buf0
        llds16(gA + (size_t)(i * 8) * lda, ldsA + i * 8 * 64);
    #pragma unroll
    for (int i = 0; i < WN/32; i++)
        llds16(gB + (size_t)(i * 8) * ldb, ldsB + i * 8 * 64);

    int cur = 0;
    for (int kt = 0; kt < kTiles; kt++){
        if (kt + 1 < kTiles){
            const int nk0 = (kt + 1) * 64;
            unsigned short* lA = ldsA + (cur ^ 1) * ASZ;
            unsigned short* lB = ldsB + (cur ^ 1) * BSZ;
            #pragma unroll
            for (int i = 0; i < WM/16; i++)
                llds16(gA + (size_t)(i * 8) * lda + nk0, lA + i * 8 * 64);
            #pragma unroll
            for (int i = 0; i < WN/32; i++)
                llds16(gB + (size_t)(i * 8) * ldb + nk0, lB + i * 8 * 64);
            vmwait<NL>();
        } else {
            vmwait<0>();
        }
        __builtin_amdgcn_s_barrier();
        const unsigned short* rA = As + cur * ASZ;
        const unsigned short* rB = Bs + cur * BSZ;
        #pragma unroll
        for (int ks = 0; ks < 64; ks += 32){
            const int cpos = (((ks >> 3) + fq) ^ cxor) * 8;
            bf16x8 af[WM/16], bv[WN/16];
            #pragma unroll
            for (int i = 0; i < WM/16; i++)
                af[i] = *(const bf16x8*)(rA + (wm + i*16 + fr) * 64 + cpos);
            #pragma unroll
            for (int j = 0; j < WN/16; j++)
                bv[j] = *(const bf16x8*)(rB + (wn + j*16 + fr) * 64 + cpos);
            #pragma unroll
            for (int i = 0; i < WM/16; i++)
                #pragma unroll
                for (int j = 0; j < WN/16; j++)
                    acc[i][j] = __builtin_amdgcn_mfma_f32_16x16x32_bf16(af[i], bv[j], acc[i][j], 0, 0, 0);
        }
        lgkm0();
        __builtin_amdgcn_s_barrier();
        cur ^= 1;
    }
}

// ---------- QKV projection: y = x @ W^T, bf16 out. z=0 Q, z=1 K (row-major), z=2 V^T ----------
// r9-proven config (reverted per r16 tripwire): 1536 blocks, XCD = id%8, XCD k
// owns m-tiles [8k,8k+8) x all n x all z -> per-XCD set 8.4 MB (53.4 us,
// MfmaUtil ~40%, FETCH 41 MB).
__global__ __launch_bounds__(256, 4) void proj_gemm(
    const unsigned short* __restrict__ xb,
    const unsigned short* __restrict__ Wb,   // [3][C_][C_]
    unsigned short* __restrict__ Qb, unsigned short* __restrict__ Kb,
    unsigned short* __restrict__ Vt)
{
    __shared__ unsigned short As[128 * 64];
    __shared__ unsigned short Bs[128 * 64];
    const int L = blockIdx.x;
    const int k = L & 7, j = L >> 3;          // j in [0,192)
    const int m0 = (k * 8 + (j & 7)) * 128;
    const int n0 = ((j >> 3) & 7) * 128;
    const int z  = j >> 6;
    const unsigned short* W = Wb + (size_t)z * C_ * C_;

    floatx4 acc[4][4];
    #pragma unroll
    for (int i = 0; i < 4; i++)
        #pragma unroll
        for (int jj = 0; jj < 4; jj++) acc[i][jj] = (floatx4){0.f,0.f,0.f,0.f};
    gemm_core<64, 64>(xb, W, C_, C_, m0, n0, C_ / 64, As, Bs, acc);

    const int lane = threadIdx.x & 63, wave = threadIdx.x >> 6;
    const int wm = (wave >> 1) * 64, wn = (wave & 1) * 64;
    const int fr = lane & 15, fq = lane >> 4;

    if (z < 2){
        unsigned short* Y = z ? Kb : Qb;
        #pragma unroll
        for (int i = 0; i < 4; i++)
            #pragma unroll
            for (int jj = 0; jj < 4; jj++)
                #pragma unroll
                for (int r = 0; r < 4; r++){
                    int row = m0 + wm + i*16 + fq*4 + r;
                    int col = n0 + wn + jj*16 + fr;
                    Y[(size_t)row * C_ + col] = f2bf(acc[i][jj][r]);
                }
    } else {
        // V^T[b][d][t]; 4 acc regs = 4 consecutive t -> packed ushort4 store
        #pragma unroll
        for (int i = 0; i < 4; i++)
            #pragma unroll
            for (int jj = 0; jj < 4; jj++){
                int row = m0 + wm + i*16 + fq*4;         // token index
                int col = n0 + wn + jj*16 + fr;          // d
                int b = row / T_, t = row % T_;
                ushort4 o = make_ushort4(f2bf(acc[i][jj][0]), f2bf(acc[i][jj][1]),
                                         f2bf(acc[i][jj][2]), f2bf(acc[i][jj][3]));
                *(ushort4*)&Vt[(size_t)b * C_ * T_ + (size_t)col * T_ + t] = o;
            }
    }
}

// ---------- S = Q K^T, causal mask + unnormalized exp -> P (bf16) + fused row-sum ----------
// r13-proven: 8-wave <32,64> counted-vmcnt core (NL=4), LDS 64 KB db ->
// 2 blocks/CU = 16 waves/CU. Grid 544. H6 mapping: b = xcd>>1, pair family
// kk = 2p + (xcd&1) -> per-XCD K set = 4 MB = one L2.
// Logits bounded -> no max pass. Row sums via per-row atomicAdd (<=17/row).
__global__ __launch_bounds__(512, 4) void score_gemm(
    const unsigned short* __restrict__ Qb, const unsigned short* __restrict__ Kb,
    unsigned short* __restrict__ P, float* __restrict__ l)
{
    const int L = blockIdx.x;
    const int xcd = L & 7, j = L >> 3;        // j in [0,68)
    const int b  = xcd >> 1;
    const int p  = j / 17, rr = j % 17;       // p in [0,4)
    const int kk = 2 * p + (xcd & 1);         // pair id 0..7
    int ti, si;
    if (rr <= 15 - kk){ ti = 15 - kk; si = rr; }
    else              { ti = kk;      si = rr - (16 - kk); }
    const int t0 = ti * 128, s0 = si * 128;

    __shared__ unsigned short As[2 * 128 * 64];   // 32 KB (db)
    __shared__ unsigned short Bs[2 * 128 * 64];   // 32 KB (db)
    floatx4 acc[2][4];
    #pragma unroll
    for (int i = 0; i < 2; i++)
        #pragma unroll
        for (int jj = 0; jj < 4; jj++) acc[i][jj] = (floatx4){0.f,0.f,0.f,0.f};
    gemm_core8_cnt<32, 64>(Qb + (size_t)b * T_ * C_, Kb + (size_t)b * T_ * C_,
                           C_, C_, t0, s0, C_ / 64, As, Bs, acc);

    const int lane = threadIdx.x & 63, wave = threadIdx.x >> 6;
    const int wm = (wave >> 1) * 32, wn = (wave & 1) * 64;
    const int fr = lane & 15, fq = lane >> 4;
    unsigned short* Pb = P + (size_t)b * T_ * T_;
    const float scale = 0.03125f;        // 1/sqrt(1024)
    float rsl[2][4];
    #pragma unroll
    for (int i = 0; i < 2; i++)
        #pragma unroll
        for (int r2 = 0; r2 < 4; r2++) rsl[i][r2] = 0.f;

    #pragma unroll
    for (int i = 0; i < 2; i++)
        #pragma unroll
        for (int jj = 0; jj < 4; jj++)
            #pragma unroll
            for (int r2 = 0; r2 < 4; r2++){
                int t = t0 + wm + i*16 + fq*4 + r2;
                int s = s0 + wn + jj*16 + fr;
                float v = (s <= t) ? __expf(acc[i][jj][r2] * scale) : 0.f;
                rsl[i][r2] += v;
                Pb[(size_t)t * T_ + s] = f2bf(v);
            }
    // reduce across the 16-lane fr group; one atomic per (row, wave)
    #pragma unroll
    for (int i = 0; i < 2; i++)
        #pragma unroll
        for (int r2 = 0; r2 < 4; r2++){
            float v = rsl[i][r2];
            v += __shfl_xor(v, 1, 64);
            v += __shfl_xor(v, 2, 64);
            v += __shfl_xor(v, 4, 64);
            v += __shfl_xor(v, 8, 64);
            if (fr == 0){
                int t = t0 + wm + i*16 + fq*4 + r2;
                atomicAdd(&l[(size_t)b * T_ + t], v);
            }
        }
}

// ---------- O = (P V) / l ----------
// r13-proven: counted-vmcnt db core (NL=6), LDS 48 KB, uniform grid 512
// (every block exactly 34 kt). H6 mapping: b = xcd>>1, kk = 2p+(xcd&1);
// per-XCD Vt set = 4 MB = one L2; P[b] read by the XCD-pair that wrote it.
__global__ __launch_bounds__(256, 4) void pv_gemm(
    const unsigned short* __restrict__ P, const unsigned short* __restrict__ Vt,
    const float* __restrict__ l, float* __restrict__ out)
{
    const int L = blockIdx.x;
    const int xcd = L & 7, j = L >> 3;        // j in [0,64)
    const int b  = xcd >> 1;
    const int p  = j >> 4;                    // 0..3
    const int n0 = (j & 15) * 64;             // d tile (64 wide)
    const int kk = 2 * p + (xcd & 1);         // pair id 0..7

    __shared__ unsigned short As[2 * 128 * 64];   // 32 KB (db)
    __shared__ unsigned short Bs[2 * 64 * 64];    // 16 KB (db)

    const int lane = threadIdx.x & 63, wave = threadIdx.x >> 6;
    const int wm = (wave >> 1) * 64, wn = (wave & 1) * 32;
    const int fr = lane & 15, fq = lane >> 4;
    float* ob = out + (size_t)b * T_ * C_;
    const float* lb = l + (size_t)b * T_;

    #pragma unroll
    for (int phase = 0; phase < 2; phase++){
        const int ti = phase ? kk : (15 - kk);  // long tile first
        const int t0 = ti * 128;
        const int kTiles = 2 * (ti + 1);        // causal: keys s < t0+128

        floatx4 acc[4][2];
        #pragma unroll
        for (int i = 0; i < 4; i++)
            #pragma unroll
            for (int jj = 0; jj < 2; jj++) acc[i][jj] = (floatx4){0.f,0.f,0.f,0.f};
        gemm_core_cnt<64, 32>(P + (size_t)b * T_ * T_, Vt + (size_t)b * C_ * T_,
                              T_, T_, t0, n0, kTiles, As, Bs, acc);

        #pragma unroll
        for (int i = 0; i < 4; i++){
            float inv[4];
            #pragma unroll
            for (int r2 = 0; r2 < 4; r2++)
                inv[r2] = 1.f / lb[t0 + wm + i*16 + fq*4 + r2];
            #pragma unroll
            for (int jj = 0; jj < 2; jj++)
                #pragma unroll
                for (int r2 = 0; r2 < 4; r2++){
                    int t = t0 + wm + i*16 + fq*4 + r2;
                    int d = n0 + wn + jj*16 + fr;
                    ob[(size_t)t * C_ + d] = acc[i][jj][r2] * inv[r2];
                }
        }
    }
}

extern "C" void kernel_launch(void* const* d_in, const int* in_sizes, int n_in,
                              void* d_out, int out_size, void* d_ws, size_t ws_size,
                              hipStream_t stream)
{
    const float* x  = (const float*)d_in[0];
    const float* Wq = (const float*)d_in[1];
    const float* Wk = (const float*)d_in[2];
    const float* Wv = (const float*)d_in[3];
    float* out = (float*)d_out;

    // ws layout (bf16 elems): Qb | Kb | Vt | P | l(fp32). xb/Wb alias P's region
    // (written by cast, read by proj, then overwritten by score_gemm -- stream-ordered;
    // l lies beyond P's 33.5 MB so it never aliases xb/Wb).
    unsigned short* Qb = (unsigned short*)d_ws;
    unsigned short* Kb = Qb + (size_t)M_ * C_;
    unsigned short* Vt = Kb + (size_t)M_ * C_;
    unsigned short* P  = Vt + (size_t)M_ * C_;
    float* l = (float*)(P + (size_t)M_ * T_);
    unsigned short* xb = P;
    unsigned short* Wb = P + (size_t)M_ * C_;

    cast_all<<<(NX_ + 3 * NW_ + NL4_ + 255) / 256, 256, 0, stream>>>(
        x, Wq, Wk, Wv, xb, Wb, l);
    proj_gemm <<<1536, 256, 0, stream>>>(xb, Wb, Qb, Kb, Vt);
    score_gemm<<<544, 512, 0, stream>>>(Qb, Kb, P, l);
    pv_gemm   <<<512, 256, 0, stream>>>(P, Vt, l, out);
}